// Round 2
// baseline (241.700 us; speedup 1.0000x reference)
//
#include <hip/hip_runtime.h>

// LIF scan over T=8, N=4M neurons, fp32. Memory-bound: ~256 MiB traffic,
// roofline ~43 us @ 6.3 TB/s. R1 lesson: compiler sank the batched loads
// (VGPR=24 -> only ~1 outstanding load/wave, 2.3 TB/s). R2: force 16
// outstanding global_load_dwordx4 per wave via sched_barrier(0) + 2 columns
// per thread; nontemporal stores keep the L3 input-resident.

#define LIF_THRESH 0.5f
#define LIF_BETA   0.25f
#define LIF_T      8

typedef float v4f __attribute__((ext_vector_type(4)));

__device__ __forceinline__ float lif_step(float& m, float xv) {
    m = m * LIF_BETA + xv;
    float s = (m >= LIF_THRESH) ? 1.f : 0.f;
    m = (m >= LIF_THRESH) ? 0.f : m;
    return s;
}

__global__ __launch_bounds__(256) void lif_kernel(const v4f* __restrict__ x,
                                                  v4f* __restrict__ out,
                                                  int n4, int half) {
    int tid = blockIdx.x * 256 + threadIdx.x;
    if (tid >= half) return;
    const int ia = tid;          // column A
    const int ib = tid + half;   // column B (still coalesced: lane i -> addr i)

    // Issue ALL 16 loads before any consumer. sched_barrier(0) pins ordering
    // (nothing crosses) without forcing a waitcnt -> 16 loads in flight/wave.
    v4f xa[LIF_T], xb[LIF_T];
#pragma unroll
    for (int t = 0; t < LIF_T; ++t) xa[t] = x[(size_t)t * n4 + ia];
#pragma unroll
    for (int t = 0; t < LIF_T; ++t) xb[t] = x[(size_t)t * n4 + ib];
    __builtin_amdgcn_sched_barrier(0);

    float ma0 = 0.f, ma1 = 0.f, ma2 = 0.f, ma3 = 0.f;
    float mb0 = 0.f, mb1 = 0.f, mb2 = 0.f, mb3 = 0.f;
#pragma unroll
    for (int t = 0; t < LIF_T; ++t) {
        v4f sa, sb;
        sa.x = lif_step(ma0, xa[t].x);
        sa.y = lif_step(ma1, xa[t].y);
        sa.z = lif_step(ma2, xa[t].z);
        sa.w = lif_step(ma3, xa[t].w);
        sb.x = lif_step(mb0, xb[t].x);
        sb.y = lif_step(mb1, xb[t].y);
        sb.z = lif_step(mb2, xb[t].z);
        sb.w = lif_step(mb3, xb[t].w);
        // Nontemporal: spike output is never re-read by us; don't let 128 MiB
        // of writes evict the L3-resident input.
        __builtin_nontemporal_store(sa, &out[(size_t)t * n4 + ia]);
        __builtin_nontemporal_store(sb, &out[(size_t)t * n4 + ib]);
    }
}

extern "C" void kernel_launch(void* const* d_in, const int* in_sizes, int n_in,
                              void* d_out, int out_size, void* d_ws, size_t ws_size,
                              hipStream_t stream) {
    const v4f* x = (const v4f*)d_in[0];
    v4f* out = (v4f*)d_out;

    long long total = in_sizes[0];
    int n = (int)(total / LIF_T);   // 4,194,304 floats per timestep
    int n4 = n / 4;                 // 1,048,576 float4 per timestep
    int half = n4 / 2;              // 524,288 threads, 2 columns each

    dim3 block(256);
    dim3 grid((half + 255) / 256);  // 2048 blocks
    lif_kernel<<<grid, block, 0, stream>>>(x, out, n4, half);
}